// Round 1
// baseline (1055.995 us; speedup 1.0000x reference)
//
#include <hip/hip_runtime.h>
#include <hip/hip_bf16.h>

// GCN: x=emb[ids]; x1=relu(GCNConv(x,W1,b1)); y=Ahat@x1; out[g]=b2+(mean_g y)@W2
// Ahat = sym-normalized adjacency with self loops (norm = dinv[src]*dinv[dst]).
//
// Restructuring:
//  - conv1: h1 = (emb@W1)[type]  (rank-17 input -> 17x128 table t1)
//  - conv2: aggregation commutes with @W2 and mean-pool -> pool y, GEMM last.
//  - dst-CSR built once (deg -> scan -> fill), self loops analytic.

#define DDIM 128

__global__ void k_deg_cnt(const int* __restrict__ dst, const int* __restrict__ batch,
                          int* __restrict__ deg, int* __restrict__ cnt, int E, int N) {
    int i = blockIdx.x * blockDim.x + threadIdx.x;
    int stride = gridDim.x * blockDim.x;
    for (int e = i; e < E; e += stride) atomicAdd(&deg[dst[e]], 1);
    for (int n = i; n < N; n += stride) atomicAdd(&cnt[batch[n]], 1);
}

// nd[i] = {dinv_i, type_i bits}; deg here is edge-only indegree, +1 self loop.
__global__ void k_pack(const int* __restrict__ deg, const int* __restrict__ ids,
                       float2* __restrict__ nd, int N) {
    int i = blockIdx.x * blockDim.x + threadIdx.x;
    if (i < N) {
        float dinv = rsqrtf((float)(deg[i] + 1));
        nd[i] = make_float2(dinv, __int_as_float(ids[i]));
    }
}

// ---- 3-kernel exclusive scan of deg -> rowStart ----
__global__ void k_scan1(const int* __restrict__ deg, int* __restrict__ rowStart,
                        int* __restrict__ blockSums, int N) {
    __shared__ int sm[1024];
    int t = threadIdx.x, i = blockIdx.x * 1024 + t;
    int v = (i < N) ? deg[i] : 0;
    sm[t] = v; __syncthreads();
    for (int off = 1; off < 1024; off <<= 1) {
        int a = (t >= off) ? sm[t - off] : 0;
        __syncthreads();
        sm[t] += a; __syncthreads();
    }
    int incl = sm[t];
    if (i < N) rowStart[i] = incl - v;          // exclusive, block-local
    if (t == 1023) blockSums[blockIdx.x] = incl; // block total
}

__global__ void k_scan2(int* __restrict__ blockSums, int* __restrict__ blockOff, int nb) {
    __shared__ int sm[256];
    int t = threadIdx.x;
    int v = (t < nb) ? blockSums[t] : 0;
    sm[t] = v; __syncthreads();
    for (int off = 1; off < 256; off <<= 1) {
        int a = (t >= off) ? sm[t - off] : 0;
        __syncthreads();
        sm[t] += a; __syncthreads();
    }
    if (t < nb) blockOff[t] = sm[t] - v;        // exclusive
}

__global__ void k_scan3(int* __restrict__ rowStart, const int* __restrict__ blockOff,
                        int N, int E) {
    int t = threadIdx.x, i = blockIdx.x * 1024 + t;
    if (i < N) rowStart[i] += blockOff[blockIdx.x];
    if (i == 0) rowStart[N] = E;
}

__global__ void k_fill(const int* __restrict__ src, const int* __restrict__ dst,
                       const int* __restrict__ rowStart, int* __restrict__ cursor,
                       int* __restrict__ csr, int E) {
    int i = blockIdx.x * blockDim.x + threadIdx.x;
    int stride = gridDim.x * blockDim.x;
    for (int e = i; e < E; e += stride) {
        int d = dst[e];
        int p = atomicAdd(&cursor[d], 1);
        csr[rowStart[d] + p] = src[e];
    }
}

// t1 = emb @ W1  (17 x 128)
__global__ void k_t1(const float* __restrict__ emb, const float* __restrict__ W1,
                     float* __restrict__ t1) {
    int t = blockIdx.x, f = threadIdx.x;
    float acc = 0.f;
    for (int k = 0; k < DDIM; k++) acc += emb[t * DDIM + k] * W1[k * DDIM + f];
    t1[t * DDIM + f] = acc;
}

// x1[i] = relu(b1 + dinv_i * (sum_e dinv_s * t1[type_s] + dinv_i * t1[type_i]))
__global__ void __launch_bounds__(128) k_conv1(
        const float2* __restrict__ nd, const int* __restrict__ rowStart,
        const int* __restrict__ csr, const float* __restrict__ t1,
        const float* __restrict__ b1, float* __restrict__ x1) {
    int i = blockIdx.x, f = threadIdx.x;
    float2 ndi = nd[i];
    float dinv_i = ndi.x;
    int ti = __float_as_int(ndi.y);
    float acc = dinv_i * t1[ti * DDIM + f];     // self loop (outer *dinv_i -> dinv_i^2)
    int e0 = rowStart[i], e1 = rowStart[i + 1];
    int e = e0;
    for (; e + 1 < e1; e += 2) {                // 2-wide for memory-level parallelism
        int s0 = csr[e], s1 = csr[e + 1];
        float2 n0 = nd[s0], n1 = nd[s1];
        acc += n0.x * t1[__float_as_int(n0.y) * DDIM + f]
             + n1.x * t1[__float_as_int(n1.y) * DDIM + f];
    }
    if (e < e1) {
        int s = csr[e];
        float2 ns = nd[s];
        acc += ns.x * t1[__float_as_int(ns.y) * DDIM + f];
    }
    float v = b1[f] + dinv_i * acc;
    x1[i * DDIM + f] = v > 0.f ? v : 0.f;
}

// y[i] = dinv_i*(sum_e dinv_s*x1[s] + dinv_i*x1[i]); poolY[batch[i]] += y[i]
#define NB 16
__global__ void __launch_bounds__(128) k_conv2(
        const float2* __restrict__ nd, const int* __restrict__ rowStart,
        const int* __restrict__ csr, const float* __restrict__ x1,
        const int* __restrict__ batch, float* __restrict__ poolY, int N) {
    int f = threadIdx.x;
    int i0 = blockIdx.x * NB;
    int iend = i0 + NB; if (iend > N) iend = N;
    float poolAcc = 0.f;
    int curG = batch[i0];
    for (int i = i0; i < iend; i++) {
        int g = batch[i];
        if (g != curG) {
            atomicAdd(&poolY[curG * DDIM + f], poolAcc);
            poolAcc = 0.f; curG = g;
        }
        float dinv_i = nd[i].x;
        float acc = dinv_i * x1[i * DDIM + f];  // self loop
        int e0 = rowStart[i], e1 = rowStart[i + 1];
        int e = e0;
        for (; e + 1 < e1; e += 2) {            // 2-wide MLP on the random gather
            int s0 = csr[e], s1 = csr[e + 1];
            float d0 = nd[s0].x, d1 = nd[s1].x;
            float v0 = x1[s0 * DDIM + f], v1 = x1[s1 * DDIM + f];
            acc += d0 * v0 + d1 * v1;
        }
        if (e < e1) {
            int s = csr[e];
            acc += nd[s].x * x1[s * DDIM + f];
        }
        poolAcc += dinv_i * acc;
    }
    atomicAdd(&poolY[curG * DDIM + f], poolAcc);
}

// out[g] = b2 + (poolY[g]/cnt[g]) @ W2 ; cnt==0 -> 0 (matches ref's sums/max(cnt,1))
__global__ void k_out(const float* __restrict__ poolY, const int* __restrict__ cnt,
                      const float* __restrict__ W2, const float* __restrict__ b2,
                      float* __restrict__ out) {
    int g = blockIdx.x, f = threadIdx.x;
    float acc = 0.f;
    for (int k = 0; k < DDIM; k++) acc += poolY[g * DDIM + k] * W2[k * DDIM + f];
    int c = cnt[g];
    out[g * DDIM + f] = (c > 0) ? (b2[f] + acc / (float)c) : 0.f;
}

extern "C" void kernel_launch(void* const* d_in, const int* in_sizes, int n_in,
                              void* d_out, int out_size, void* d_ws, size_t ws_size,
                              hipStream_t stream) {
    const int* node_ids = (const int*)d_in[0];
    const int* edge_index = (const int*)d_in[1];
    const int* batch = (const int*)d_in[2];
    const float* emb = (const float*)d_in[4];
    const float* W1 = (const float*)d_in[5];
    const float* b1 = (const float*)d_in[6];
    const float* W2 = (const float*)d_in[7];
    const float* b2 = (const float*)d_in[8];
    float* out = (float*)d_out;

    const int N = in_sizes[0];
    const int E = in_sizes[1] / 2;
    const int G = out_size / DDIM;
    const int* src = edge_index;
    const int* dst = edge_index + E;

    // workspace carve-up (256B aligned)
    char* ws = (char*)d_ws;
    size_t off = 0;
    auto carve = [&](size_t bytes) { char* p = ws + off; off = (off + bytes + 255) & ~size_t(255); return p; };
    float*  x1       = (float*)carve((size_t)N * DDIM * 4);
    int*    csr      = (int*)carve((size_t)E * 4);
    float2* nd       = (float2*)carve((size_t)N * 8);
    int*    deg      = (int*)carve((size_t)N * 4);
    int*    rowStart = (int*)carve((size_t)(N + 1) * 4);
    int*    cursor   = (int*)carve((size_t)N * 4);
    int*    blockSums= (int*)carve(1024);
    int*    blockOff = (int*)carve(1024);
    float*  t1       = (float*)carve(17 * DDIM * 4);
    float*  poolY    = (float*)carve((size_t)G * DDIM * 4);
    int*    cnt      = (int*)carve((size_t)G * 4);

    hipMemsetAsync(deg,    0, (size_t)N * 4, stream);
    hipMemsetAsync(cursor, 0, (size_t)N * 4, stream);
    hipMemsetAsync(poolY,  0, (size_t)G * DDIM * 4, stream);
    hipMemsetAsync(cnt,    0, (size_t)G * 4, stream);

    k_deg_cnt<<<2048, 256, 0, stream>>>(dst, batch, deg, cnt, E, N);

    int nb = (N + 1023) / 1024;   // 98 for N=100000 (must be <= 256)
    k_scan1<<<nb, 1024, 0, stream>>>(deg, rowStart, blockSums, N);
    k_scan2<<<1, 256, 0, stream>>>(blockSums, blockOff, nb);
    k_scan3<<<nb, 1024, 0, stream>>>(rowStart, blockOff, N, E);

    k_pack<<<(N + 255) / 256, 256, 0, stream>>>(deg, node_ids, nd, N);
    k_fill<<<2048, 256, 0, stream>>>(src, dst, rowStart, cursor, csr, E);

    k_t1<<<17, DDIM, 0, stream>>>(emb, W1, t1);
    k_conv1<<<N, DDIM, 0, stream>>>(nd, rowStart, csr, t1, b1, x1);
    k_conv2<<<(N + NB - 1) / NB, DDIM, 0, stream>>>(nd, rowStart, csr, x1, batch, poolY, N);
    k_out<<<G, DDIM, 0, stream>>>(poolY, cnt, W2, b2, out);
}

// Round 2
// 541.874 us; speedup vs baseline: 1.9488x; 1.9488x over previous
//
#include <hip/hip_runtime.h>
#include <hip/hip_bf16.h>

// GCN: x=emb[ids]; x1=relu(GCNConv(x,W1,b1)); y=Ahat@x1; out[g]=b2+(mean_g y)@W2
// Ahat = sym-normalized adjacency with self loops (norm = dinv[src]*dinv[dst]).
//
// Restructuring:
//  - conv1: h1 = (emb@W1)[type]  (rank-17 input -> 17x128 table t1)
//  - conv2: aggregation commutes with @W2 and mean-pool -> pool y, GEMM last.
//  - dst-CSR built once (deg -> scan -> fill), self loops analytic.
//  - R1: graph counts via binary search on sorted batch (was: 100k atomics on
//    64 addrs with wave-uniform address -> 64-way same-address serialization,
//    573 us = 54% of runtime).

#define DDIM 128

__global__ void k_deg(const int* __restrict__ dst, int* __restrict__ deg, int E) {
    int i = blockIdx.x * blockDim.x + threadIdx.x;
    int stride = gridDim.x * blockDim.x;
    for (int e = i; e < E; e += stride) atomicAdd(&deg[dst[e]], 1);
}

// batch is sorted: cnt[g] = lower_bound(g+1) - lower_bound(g). No atomics.
__global__ void k_cnt(const int* __restrict__ batch, int* __restrict__ cnt,
                      int N, int G) {
    int g = threadIdx.x;
    if (g >= G) return;
    auto lb = [&](int key) {   // first index with batch[i] >= key
        int lo = 0, hi = N;
        while (lo < hi) {
            int mid = (lo + hi) >> 1;
            if (batch[mid] < key) lo = mid + 1; else hi = mid;
        }
        return lo;
    };
    cnt[g] = lb(g + 1) - lb(g);
}

// nd[i] = {dinv_i, type_i bits}; deg here is edge-only indegree, +1 self loop.
__global__ void k_pack(const int* __restrict__ deg, const int* __restrict__ ids,
                       float2* __restrict__ nd, int N) {
    int i = blockIdx.x * blockDim.x + threadIdx.x;
    if (i < N) {
        float dinv = rsqrtf((float)(deg[i] + 1));
        nd[i] = make_float2(dinv, __int_as_float(ids[i]));
    }
}

// ---- 3-kernel exclusive scan of deg -> rowStart ----
__global__ void k_scan1(const int* __restrict__ deg, int* __restrict__ rowStart,
                        int* __restrict__ blockSums, int N) {
    __shared__ int sm[1024];
    int t = threadIdx.x, i = blockIdx.x * 1024 + t;
    int v = (i < N) ? deg[i] : 0;
    sm[t] = v; __syncthreads();
    for (int off = 1; off < 1024; off <<= 1) {
        int a = (t >= off) ? sm[t - off] : 0;
        __syncthreads();
        sm[t] += a; __syncthreads();
    }
    int incl = sm[t];
    if (i < N) rowStart[i] = incl - v;          // exclusive, block-local
    if (t == 1023) blockSums[blockIdx.x] = incl; // block total
}

__global__ void k_scan2(int* __restrict__ blockSums, int* __restrict__ blockOff, int nb) {
    __shared__ int sm[256];
    int t = threadIdx.x;
    int v = (t < nb) ? blockSums[t] : 0;
    sm[t] = v; __syncthreads();
    for (int off = 1; off < 256; off <<= 1) {
        int a = (t >= off) ? sm[t - off] : 0;
        __syncthreads();
        sm[t] += a; __syncthreads();
    }
    if (t < nb) blockOff[t] = sm[t] - v;        // exclusive
}

__global__ void k_scan3(int* __restrict__ rowStart, const int* __restrict__ blockOff,
                        int N, int E) {
    int t = threadIdx.x, i = blockIdx.x * 1024 + t;
    if (i < N) rowStart[i] += blockOff[blockIdx.x];
    if (i == 0) rowStart[N] = E;
}

__global__ void k_fill(const int* __restrict__ src, const int* __restrict__ dst,
                       const int* __restrict__ rowStart, int* __restrict__ cursor,
                       int* __restrict__ csr, int E) {
    int i = blockIdx.x * blockDim.x + threadIdx.x;
    int stride = gridDim.x * blockDim.x;
    for (int e = i; e < E; e += stride) {
        int d = dst[e];
        int p = atomicAdd(&cursor[d], 1);
        csr[rowStart[d] + p] = src[e];
    }
}

// t1 = emb @ W1  (17 x 128)
__global__ void k_t1(const float* __restrict__ emb, const float* __restrict__ W1,
                     float* __restrict__ t1) {
    int t = blockIdx.x, f = threadIdx.x;
    float acc = 0.f;
    for (int k = 0; k < DDIM; k++) acc += emb[t * DDIM + k] * W1[k * DDIM + f];
    t1[t * DDIM + f] = acc;
}

// x1[i] = relu(b1 + dinv_i * (sum_e dinv_s * t1[type_s] + dinv_i * t1[type_i]))
__global__ void __launch_bounds__(128) k_conv1(
        const float2* __restrict__ nd, const int* __restrict__ rowStart,
        const int* __restrict__ csr, const float* __restrict__ t1,
        const float* __restrict__ b1, float* __restrict__ x1) {
    int i = blockIdx.x, f = threadIdx.x;
    float2 ndi = nd[i];
    float dinv_i = ndi.x;
    int ti = __float_as_int(ndi.y);
    float acc = dinv_i * t1[ti * DDIM + f];     // self loop (outer *dinv_i -> dinv_i^2)
    int e0 = rowStart[i], e1 = rowStart[i + 1];
    int e = e0;
    for (; e + 1 < e1; e += 2) {                // 2-wide for memory-level parallelism
        int s0 = csr[e], s1 = csr[e + 1];
        float2 n0 = nd[s0], n1 = nd[s1];
        acc += n0.x * t1[__float_as_int(n0.y) * DDIM + f]
             + n1.x * t1[__float_as_int(n1.y) * DDIM + f];
    }
    if (e < e1) {
        int s = csr[e];
        float2 ns = nd[s];
        acc += ns.x * t1[__float_as_int(ns.y) * DDIM + f];
    }
    float v = b1[f] + dinv_i * acc;
    x1[i * DDIM + f] = v > 0.f ? v : 0.f;
}

// y[i] = dinv_i*(sum_e dinv_s*x1[s] + dinv_i*x1[i]); poolY[batch[i]] += y[i]
#define NB 16
__global__ void __launch_bounds__(128) k_conv2(
        const float2* __restrict__ nd, const int* __restrict__ rowStart,
        const int* __restrict__ csr, const float* __restrict__ x1,
        const int* __restrict__ batch, float* __restrict__ poolY, int N) {
    int f = threadIdx.x;
    int i0 = blockIdx.x * NB;
    int iend = i0 + NB; if (iend > N) iend = N;
    float poolAcc = 0.f;
    int curG = batch[i0];
    for (int i = i0; i < iend; i++) {
        int g = batch[i];
        if (g != curG) {
            atomicAdd(&poolY[curG * DDIM + f], poolAcc);
            poolAcc = 0.f; curG = g;
        }
        float dinv_i = nd[i].x;
        float acc = dinv_i * x1[i * DDIM + f];  // self loop
        int e0 = rowStart[i], e1 = rowStart[i + 1];
        int e = e0;
        for (; e + 1 < e1; e += 2) {            // 2-wide MLP on the random gather
            int s0 = csr[e], s1 = csr[e + 1];
            float d0 = nd[s0].x, d1 = nd[s1].x;
            float v0 = x1[s0 * DDIM + f], v1 = x1[s1 * DDIM + f];
            acc += d0 * v0 + d1 * v1;
        }
        if (e < e1) {
            int s = csr[e];
            acc += nd[s].x * x1[s * DDIM + f];
        }
        poolAcc += dinv_i * acc;
    }
    atomicAdd(&poolY[curG * DDIM + f], poolAcc);
}

// out[g] = b2 + (poolY[g]/cnt[g]) @ W2 ; cnt==0 -> 0 (matches ref's sums/max(cnt,1))
__global__ void k_out(const float* __restrict__ poolY, const int* __restrict__ cnt,
                      const float* __restrict__ W2, const float* __restrict__ b2,
                      float* __restrict__ out) {
    int g = blockIdx.x, f = threadIdx.x;
    float acc = 0.f;
    for (int k = 0; k < DDIM; k++) acc += poolY[g * DDIM + k] * W2[k * DDIM + f];
    int c = cnt[g];
    out[g * DDIM + f] = (c > 0) ? (b2[f] + acc / (float)c) : 0.f;
}

extern "C" void kernel_launch(void* const* d_in, const int* in_sizes, int n_in,
                              void* d_out, int out_size, void* d_ws, size_t ws_size,
                              hipStream_t stream) {
    const int* node_ids = (const int*)d_in[0];
    const int* edge_index = (const int*)d_in[1];
    const int* batch = (const int*)d_in[2];
    const float* emb = (const float*)d_in[4];
    const float* W1 = (const float*)d_in[5];
    const float* b1 = (const float*)d_in[6];
    const float* W2 = (const float*)d_in[7];
    const float* b2 = (const float*)d_in[8];
    float* out = (float*)d_out;

    const int N = in_sizes[0];
    const int E = in_sizes[1] / 2;
    const int G = out_size / DDIM;
    const int* src = edge_index;
    const int* dst = edge_index + E;

    // workspace carve-up (256B aligned)
    char* ws = (char*)d_ws;
    size_t off = 0;
    auto carve = [&](size_t bytes) { char* p = ws + off; off = (off + bytes + 255) & ~size_t(255); return p; };
    float*  x1       = (float*)carve((size_t)N * DDIM * 4);
    int*    csr      = (int*)carve((size_t)E * 4);
    float2* nd       = (float2*)carve((size_t)N * 8);
    int*    deg      = (int*)carve((size_t)N * 4);
    int*    rowStart = (int*)carve((size_t)(N + 1) * 4);
    int*    cursor   = (int*)carve((size_t)N * 4);
    int*    blockSums= (int*)carve(1024);
    int*    blockOff = (int*)carve(1024);
    float*  t1       = (float*)carve(17 * DDIM * 4);
    float*  poolY    = (float*)carve((size_t)G * DDIM * 4);
    int*    cnt      = (int*)carve((size_t)G * 4);

    hipMemsetAsync(deg,    0, (size_t)N * 4, stream);
    hipMemsetAsync(cursor, 0, (size_t)N * 4, stream);
    hipMemsetAsync(poolY,  0, (size_t)G * DDIM * 4, stream);

    k_deg<<<2048, 256, 0, stream>>>(dst, deg, E);
    k_cnt<<<1, 64, 0, stream>>>(batch, cnt, N, G);

    int nb = (N + 1023) / 1024;   // 98 for N=100000 (must be <= 256)
    k_scan1<<<nb, 1024, 0, stream>>>(deg, rowStart, blockSums, N);
    k_scan2<<<1, 256, 0, stream>>>(blockSums, blockOff, nb);
    k_scan3<<<nb, 1024, 0, stream>>>(rowStart, blockOff, N, E);

    k_pack<<<(N + 255) / 256, 256, 0, stream>>>(deg, node_ids, nd, N);
    k_fill<<<2048, 256, 0, stream>>>(src, dst, rowStart, cursor, csr, E);

    k_t1<<<17, DDIM, 0, stream>>>(emb, W1, t1);
    k_conv1<<<N, DDIM, 0, stream>>>(nd, rowStart, csr, t1, b1, x1);
    k_conv2<<<(N + NB - 1) / NB, DDIM, 0, stream>>>(nd, rowStart, csr, x1, batch, poolY, N);
    k_out<<<G, DDIM, 0, stream>>>(poolY, cnt, W2, b2, out);
}

// Round 3
// 489.431 us; speedup vs baseline: 2.1576x; 1.1072x over previous
//
#include <hip/hip_runtime.h>
#include <hip/hip_bf16.h>

// GCN: x=emb[ids]; x1=relu(GCNConv(x,W1,b1)); y=Ahat@x1; out[g]=b2+(mean_g y)@W2
// Ahat = sym-normalized adjacency with self loops (norm = dinv[src]*dinv[dst]).
//
// Restructuring:
//  - conv1: h1 = (emb@W1)[type]  (rank-17 input -> 17x128 table t1)
//  - conv2: aggregation commutes with @W2 and mean-pool -> pool y, GEMM last.
//  - dst-CSR built once (deg -> scan -> fill), self loops analytic.
//  - R1: graph counts via binary search on sorted batch (no 64-addr atomics).
//  - R2: x1 stored bf16 (halves the 870 MB conv2 gather stream + conv1 write);
//        convs use 64 lanes/row, 1 dword (bf16x2) per lane, 4-wave blocks.

#define DDIM 128
typedef unsigned int uint;

__device__ __forceinline__ float bflo(uint v) { return __uint_as_float(v << 16); }
__device__ __forceinline__ float bfhi(uint v) { return __uint_as_float(v & 0xffff0000u); }
__device__ __forceinline__ uint packbf(float x, float y) {  // RNE round both
    uint ux = __float_as_uint(x), uy = __float_as_uint(y);
    ux = (ux + 0x7fff + ((ux >> 16) & 1)) >> 16;
    uy = (uy + 0x7fff + ((uy >> 16) & 1)) & 0xffff0000u;
    return ux | uy;
}

__global__ void k_deg(const int* __restrict__ dst, int* __restrict__ deg, int E) {
    int i = blockIdx.x * blockDim.x + threadIdx.x;
    int stride = gridDim.x * blockDim.x;
    for (int e = i; e < E; e += stride) atomicAdd(&deg[dst[e]], 1);
}

// batch is sorted: cnt[g] = lower_bound(g+1) - lower_bound(g). No atomics.
__global__ void k_cnt(const int* __restrict__ batch, int* __restrict__ cnt,
                      int N, int G) {
    int g = threadIdx.x;
    if (g >= G) return;
    auto lb = [&](int key) {
        int lo = 0, hi = N;
        while (lo < hi) {
            int mid = (lo + hi) >> 1;
            if (batch[mid] < key) lo = mid + 1; else hi = mid;
        }
        return lo;
    };
    cnt[g] = lb(g + 1) - lb(g);
}

// nd[i] = {dinv_i, type_i bits}; deg is edge-only indegree, +1 self loop.
__global__ void k_pack(const int* __restrict__ deg, const int* __restrict__ ids,
                       float2* __restrict__ nd, int N) {
    int i = blockIdx.x * blockDim.x + threadIdx.x;
    if (i < N) {
        float dinv = rsqrtf((float)(deg[i] + 1));
        nd[i] = make_float2(dinv, __int_as_float(ids[i]));
    }
}

// ---- 3-kernel exclusive scan of deg -> rowStart ----
__global__ void k_scan1(const int* __restrict__ deg, int* __restrict__ rowStart,
                        int* __restrict__ blockSums, int N) {
    __shared__ int sm[1024];
    int t = threadIdx.x, i = blockIdx.x * 1024 + t;
    int v = (i < N) ? deg[i] : 0;
    sm[t] = v; __syncthreads();
    for (int off = 1; off < 1024; off <<= 1) {
        int a = (t >= off) ? sm[t - off] : 0;
        __syncthreads();
        sm[t] += a; __syncthreads();
    }
    int incl = sm[t];
    if (i < N) rowStart[i] = incl - v;
    if (t == 1023) blockSums[blockIdx.x] = incl;
}

__global__ void k_scan2(int* __restrict__ blockSums, int* __restrict__ blockOff, int nb) {
    __shared__ int sm[256];
    int t = threadIdx.x;
    int v = (t < nb) ? blockSums[t] : 0;
    sm[t] = v; __syncthreads();
    for (int off = 1; off < 256; off <<= 1) {
        int a = (t >= off) ? sm[t - off] : 0;
        __syncthreads();
        sm[t] += a; __syncthreads();
    }
    if (t < nb) blockOff[t] = sm[t] - v;
}

__global__ void k_scan3(int* __restrict__ rowStart, const int* __restrict__ blockOff,
                        int N, int E) {
    int t = threadIdx.x, i = blockIdx.x * 1024 + t;
    if (i < N) rowStart[i] += blockOff[blockIdx.x];
    if (i == 0) rowStart[N] = E;
}

__global__ void k_fill(const int* __restrict__ src, const int* __restrict__ dst,
                       const int* __restrict__ rowStart, int* __restrict__ cursor,
                       int* __restrict__ csr, int E) {
    int i = blockIdx.x * blockDim.x + threadIdx.x;
    int stride = gridDim.x * blockDim.x;
    for (int e = i; e < E; e += stride) {
        int d = dst[e];
        int p = atomicAdd(&cursor[d], 1);
        csr[rowStart[d] + p] = src[e];
    }
}

// t1 = emb @ W1  (17 x 128)
__global__ void k_t1(const float* __restrict__ emb, const float* __restrict__ W1,
                     float* __restrict__ t1) {
    int t = blockIdx.x, f = threadIdx.x;
    float acc = 0.f;
    for (int k = 0; k < DDIM; k++) acc += emb[t * DDIM + k] * W1[k * DDIM + f];
    t1[t * DDIM + f] = acc;
}

// x1[i] = relu(b1 + dinv_i*(sum_e dinv_s*t1[type_s] + dinv_i*t1[type_i]))  -> bf16x2
// 64 lanes per row (2 features each), 4 waves/block = 4 rows/block.
__global__ void __launch_bounds__(256) k_conv1(
        const float2* __restrict__ nd, const int* __restrict__ rowStart,
        const int* __restrict__ csr, const float* __restrict__ t1,
        const float* __restrict__ b1, uint* __restrict__ x1u, int N) {
    int lane = threadIdx.x & 63, wave = threadIdx.x >> 6;
    int i = blockIdx.x * 4 + wave;
    if (i >= N) return;
    const float2* t1v = (const float2*)t1;
    float2 ndi = nd[i];
    float dinv_i = ndi.x;
    int ti = __float_as_int(ndi.y);
    float2 t = t1v[ti * 64 + lane];
    float2 acc = make_float2(dinv_i * t.x, dinv_i * t.y);   // self loop
    int e0 = rowStart[i], e1 = rowStart[i + 1];
    int e = e0;
    for (; e + 1 < e1; e += 2) {
        int s0 = csr[e], s1 = csr[e + 1];
        float2 n0 = nd[s0], n1 = nd[s1];
        float2 u0 = t1v[__float_as_int(n0.y) * 64 + lane];
        float2 u1 = t1v[__float_as_int(n1.y) * 64 + lane];
        acc.x += n0.x * u0.x + n1.x * u1.x;
        acc.y += n0.x * u0.y + n1.x * u1.y;
    }
    if (e < e1) {
        int s = csr[e];
        float2 ns = nd[s];
        float2 us = t1v[__float_as_int(ns.y) * 64 + lane];
        acc.x += ns.x * us.x;
        acc.y += ns.x * us.y;
    }
    float2 b = ((const float2*)b1)[lane];
    float vx = b.x + dinv_i * acc.x;
    float vy = b.y + dinv_i * acc.y;
    vx = vx > 0.f ? vx : 0.f;
    vy = vy > 0.f ? vy : 0.f;
    x1u[i * 64 + lane] = packbf(vx, vy);
}

// y[i] = dinv_i*(sum_e dinv_s*x1[s] + dinv_i*x1[i]); poolY[batch[i]] += y[i]
// 64 lanes/row (bf16x2 per lane), 4 waves/block, NB rows per wave.
#define NB 16
__global__ void __launch_bounds__(256) k_conv2(
        const float2* __restrict__ nd, const int* __restrict__ rowStart,
        const int* __restrict__ csr, const uint* __restrict__ x1u,
        const int* __restrict__ batch, float* __restrict__ poolY, int N) {
    int lane = threadIdx.x & 63, wave = threadIdx.x >> 6;
    int i0 = (blockIdx.x * 4 + wave) * NB;
    if (i0 >= N) return;
    int iend = i0 + NB; if (iend > N) iend = N;
    float2 poolAcc = make_float2(0.f, 0.f);
    int curG = batch[i0];
    for (int i = i0; i < iend; i++) {
        int g = batch[i];
        if (g != curG) {
            atomicAdd(&poolY[curG * DDIM + 2 * lane],     poolAcc.x);
            atomicAdd(&poolY[curG * DDIM + 2 * lane + 1], poolAcc.y);
            poolAcc = make_float2(0.f, 0.f); curG = g;
        }
        float dinv_i = nd[i].x;
        uint self = x1u[i * 64 + lane];
        float2 acc = make_float2(dinv_i * bflo(self), dinv_i * bfhi(self));
        int e0 = rowStart[i], e1 = rowStart[i + 1];
        int e = e0;
        for (; e + 3 < e1; e += 4) {          // 4-wide for memory-level parallelism
            int s0 = csr[e], s1 = csr[e + 1], s2 = csr[e + 2], s3 = csr[e + 3];
            float d0 = nd[s0].x, d1 = nd[s1].x, d2 = nd[s2].x, d3 = nd[s3].x;
            uint v0 = x1u[s0 * 64 + lane], v1 = x1u[s1 * 64 + lane];
            uint v2 = x1u[s2 * 64 + lane], v3 = x1u[s3 * 64 + lane];
            acc.x += d0 * bflo(v0) + d1 * bflo(v1) + d2 * bflo(v2) + d3 * bflo(v3);
            acc.y += d0 * bfhi(v0) + d1 * bfhi(v1) + d2 * bfhi(v2) + d3 * bfhi(v3);
        }
        for (; e < e1; e++) {
            int s = csr[e];
            float d = nd[s].x;
            uint v = x1u[s * 64 + lane];
            acc.x += d * bflo(v);
            acc.y += d * bfhi(v);
        }
        poolAcc.x += dinv_i * acc.x;
        poolAcc.y += dinv_i * acc.y;
    }
    atomicAdd(&poolY[curG * DDIM + 2 * lane],     poolAcc.x);
    atomicAdd(&poolY[curG * DDIM + 2 * lane + 1], poolAcc.y);
}

// out[g] = b2 + (poolY[g]/cnt[g]) @ W2 ; cnt==0 -> 0
__global__ void k_out(const float* __restrict__ poolY, const int* __restrict__ cnt,
                      const float* __restrict__ W2, const float* __restrict__ b2,
                      float* __restrict__ out) {
    int g = blockIdx.x, f = threadIdx.x;
    float acc = 0.f;
    for (int k = 0; k < DDIM; k++) acc += poolY[g * DDIM + k] * W2[k * DDIM + f];
    int c = cnt[g];
    out[g * DDIM + f] = (c > 0) ? (b2[f] + acc / (float)c) : 0.f;
}

extern "C" void kernel_launch(void* const* d_in, const int* in_sizes, int n_in,
                              void* d_out, int out_size, void* d_ws, size_t ws_size,
                              hipStream_t stream) {
    const int* node_ids = (const int*)d_in[0];
    const int* edge_index = (const int*)d_in[1];
    const int* batch = (const int*)d_in[2];
    const float* emb = (const float*)d_in[4];
    const float* W1 = (const float*)d_in[5];
    const float* b1 = (const float*)d_in[6];
    const float* W2 = (const float*)d_in[7];
    const float* b2 = (const float*)d_in[8];
    float* out = (float*)d_out;

    const int N = in_sizes[0];
    const int E = in_sizes[1] / 2;
    const int G = out_size / DDIM;
    const int* src = edge_index;
    const int* dst = edge_index + E;

    char* ws = (char*)d_ws;
    size_t off = 0;
    auto carve = [&](size_t bytes) { char* p = ws + off; off = (off + bytes + 255) & ~size_t(255); return p; };
    uint*   x1u      = (uint*)carve((size_t)N * 64 * 4);     // bf16x2 packed
    int*    csr      = (int*)carve((size_t)E * 4);
    float2* nd       = (float2*)carve((size_t)N * 8);
    int*    deg      = (int*)carve((size_t)N * 4);
    int*    rowStart = (int*)carve((size_t)(N + 1) * 4);
    int*    cursor   = (int*)carve((size_t)N * 4);
    int*    blockSums= (int*)carve(1024);
    int*    blockOff = (int*)carve(1024);
    float*  t1       = (float*)carve(17 * DDIM * 4);
    float*  poolY    = (float*)carve((size_t)G * DDIM * 4);
    int*    cnt      = (int*)carve((size_t)G * 4);

    hipMemsetAsync(deg,    0, (size_t)N * 4, stream);
    hipMemsetAsync(cursor, 0, (size_t)N * 4, stream);
    hipMemsetAsync(poolY,  0, (size_t)G * DDIM * 4, stream);

    k_deg<<<2048, 256, 0, stream>>>(dst, deg, E);
    k_cnt<<<1, 64, 0, stream>>>(batch, cnt, N, G);

    int nb = (N + 1023) / 1024;
    k_scan1<<<nb, 1024, 0, stream>>>(deg, rowStart, blockSums, N);
    k_scan2<<<1, 256, 0, stream>>>(blockSums, blockOff, nb);
    k_scan3<<<nb, 1024, 0, stream>>>(rowStart, blockOff, N, E);

    k_pack<<<(N + 255) / 256, 256, 0, stream>>>(deg, node_ids, nd, N);
    k_fill<<<2048, 256, 0, stream>>>(src, dst, rowStart, cursor, csr, E);

    k_t1<<<17, DDIM, 0, stream>>>(emb, W1, t1);
    k_conv1<<<(N + 3) / 4, 256, 0, stream>>>(nd, rowStart, csr, t1, b1, x1u, N);
    k_conv2<<<(N + 4 * NB - 1) / (4 * NB), 256, 0, stream>>>(nd, rowStart, csr, x1u, batch, poolY, N);
    k_out<<<G, DDIM, 0, stream>>>(poolY, cnt, W2, b2, out);
}